// Round 6
// baseline (376.171 us; speedup 1.0000x reference)
//
#include <hip/hip_runtime.h>

// Problem constants (match reference setup_inputs)
#define NODES 50000
#define NEDGE 1600000
#define ND 64      // NODE_DIM
#define ED 32      // EDGE_DIM
#define HID 64     // HIDDEN
#define IN_DIM 96  // ND + ED

#define TW 16        // edges per wave-private micro-tile
#define MSG_LD 104   // bf16/row: 96+8 pad -> 208 B rows (b128 reads spread 8 start-banks)
#define H_LD   72    // bf16/row: 64+8 pad -> 144 B rows (h and m overlay, same layout)

typedef __bf16 bf16_t;
typedef __bf16 bf16x4_t __attribute__((ext_vector_type(4)));
typedef __bf16 bf16x8_t __attribute__((ext_vector_type(8)));
typedef float  f32x4_t  __attribute__((ext_vector_type(4)));

#define SCAN_B 256
#define SCAN_NBLK ((NODES + SCAN_B - 1) / SCAN_B)   // 196

// ---------------- K0: zero out accumulator + counts ----------------
__global__ void zero_kernel(float* __restrict__ out, int* __restrict__ cnt) {
    int i = blockIdx.x * blockDim.x + threadIdx.x;
    int stride = gridDim.x * blockDim.x;
    const int total = NODES * ND;
    for (int idx = i; idx < total; idx += stride) out[idx] = 0.0f;
    for (int idx = i; idx < NODES; idx += stride) cnt[idx] = 0;
}

// ---------------- K1: histogram of dst ----------------
__global__ void hist_kernel(const int* __restrict__ ei, int* __restrict__ cnt) {
    int i = blockIdx.x * blockDim.x + threadIdx.x;
    int stride = gridDim.x * blockDim.x;
    for (int e = i; e < NEDGE; e += stride)
        atomicAdd(&cnt[ei[NEDGE + e]], 1);
}

// ---------------- K2a: per-block partial sums of cnt ----------------
__global__ void scan_sum_kernel(const int* __restrict__ cnt, int* __restrict__ bsum) {
    __shared__ int sh[SCAN_B];
    const int t = threadIdx.x, b = blockIdx.x;
    const int i = b * SCAN_B + t;
    sh[t] = (i < NODES) ? cnt[i] : 0;
    __syncthreads();
    for (int d = SCAN_B / 2; d > 0; d >>= 1) {
        if (t < d) sh[t] += sh[t + d];
        __syncthreads();
    }
    if (t == 0) bsum[b] = sh[0];
}

// ---------------- K2b: exclusive scan of 196 block sums (1 tiny block) ----------------
__global__ void scan_top_kernel(int* __restrict__ bsum) {
    __shared__ int sh[SCAN_B];
    const int t = threadIdx.x;
    sh[t] = (t < SCAN_NBLK) ? bsum[t] : 0;
    __syncthreads();
    for (int d = 1; d < SCAN_B; d <<= 1) {
        int v = (t >= d) ? sh[t - d] : 0;
        __syncthreads();
        sh[t] += v;
        __syncthreads();
    }
    if (t < SCAN_NBLK) bsum[t] = (t == 0) ? 0 : sh[t - 1];   // exclusive
}

// ---------------- K2c: fill cursor = global exclusive prefix of cnt ----------------
__global__ void scan_fill_kernel(const int* __restrict__ cnt, const int* __restrict__ bsum,
                                 int* __restrict__ cursor) {
    __shared__ int sh[SCAN_B];
    const int t = threadIdx.x, b = blockIdx.x;
    const int i = b * SCAN_B + t;
    int v = (i < NODES) ? cnt[i] : 0;
    sh[t] = v;
    __syncthreads();
    for (int d = 1; d < SCAN_B; d <<= 1) {
        int u = (t >= d) ? sh[t - d] : 0;
        __syncthreads();
        sh[t] += u;
        __syncthreads();
    }
    if (i < NODES) cursor[i] = bsum[b] + sh[t] - v;   // exclusive
}

// ---------------- K3: bucket-scatter edge ids (CSR perm, packed int2) ----------------
__global__ void bucket_kernel(const int* __restrict__ ei, int* __restrict__ cursor,
                              int2* __restrict__ pd) {
    int i = blockIdx.x * blockDim.x + threadIdx.x;
    int stride = gridDim.x * blockDim.x;
    for (int e = i; e < NEDGE; e += stride) {
        int d = ei[NEDGE + e];
        int pos = atomicAdd(&cursor[d], 1);
        pd[pos] = make_int2(e, d);
    }
}

// ---------------- K4: per-edge MLP via bf16 MFMA — BARRIER-FREE ----------------
// Each wave owns a private 16-edge micro-tile end-to-end in its own LDS region.
// No __syncthreads anywhere: same-wave DS ops are pipe-ordered, all LDS data is
// bf16 (uniform type => compiler keeps overlay access order), atomics free-run.
__global__ __launch_bounds__(256)
void edge_mlp_mfma(const float* __restrict__ x,
                   const float* __restrict__ edge_attr,
                   const float* __restrict__ W1, const float* __restrict__ b1,
                   const float* __restrict__ W2, const float* __restrict__ b2,
                   const int2* __restrict__ pd,
                   float* __restrict__ out_sum)
{
    constexpr int WAVE_B = TW * MSG_LD * 2;     // 3328 B: msg [16][104]; h/m overlay [16][72]
    __shared__ __align__(16) char smem[4 * WAVE_B];
    __shared__ int dstw_all[4 * TW];

    const int t    = threadIdx.x;
    const int lane = t & 63;
    const int w    = t >> 6;         // wave id 0..3
    const int col  = lane & 15;      // MFMA col / A-row selector
    const int kq   = lane >> 4;      // 0..3: k-quarter

    bf16_t* msg  = (bf16_t*)(smem + w * WAVE_B);   // [16][MSG_LD]
    bf16_t* hS   = msg;                            // [16][H_LD] overlay (h, then m)
    int*    dstw = dstw_all + w * TW;

    // ---- one-time: B-fragments + biases straight from global to registers ----
    // B-frag lane layout (16x16x32): col = lane&15, k = (lane>>4)*8 + j
    bf16x8_t w1f[4][3];
    bf16x8_t w2f[4][2];
    float b1r[4], b2r[4];
    #pragma unroll
    for (int nt = 0; nt < 4; ++nt) {
        const int cn = col + 16 * nt;
        b1r[nt] = b1[cn];
        b2r[nt] = b2[cn];
        #pragma unroll
        for (int kk = 0; kk < 3; ++kk) {
            bf16x8_t f;
            #pragma unroll
            for (int j = 0; j < 8; ++j)
                f[j] = (bf16_t)W1[(kk * 32 + kq * 8 + j) * HID + cn];
            w1f[nt][kk] = f;
        }
        #pragma unroll
        for (int kk = 0; kk < 2; ++kk) {
            bf16x8_t f;
            #pragma unroll
            for (int j = 0; j < 8; ++j)
                f[j] = (bf16_t)W2[(kk * 32 + kq * 8 + j) * ND + cn];
            w2f[nt][kk] = f;
        }
    }

    const int ntiles = NEDGE / TW;               // 100000
    const int wid = blockIdx.x * 4 + w;
    const int nw  = gridDim.x * 4;

    for (int tile = wid; tile < ntiles; tile += nw) {
        const int eb = tile * TW;

        if (lane < TW) dstw[lane] = pd[eb + lane].y;

        // ---- stage msg micro-tile (bf16): 4 lanes per edge row ----
        {
            const int e = lane >> 2, c = lane & 3;
            const int2 rec = pd[eb + e];
            const float4* xr = (const float4*)(x + (size_t)rec.y * ND);
            #pragma unroll
            for (int it = 0; it < 4; ++it) {
                const int c4 = c + it * 4;
                float4 v = xr[c4];
                bf16x4_t p = {(bf16_t)v.x, (bf16_t)v.y, (bf16_t)v.z, (bf16_t)v.w};
                *(bf16x4_t*)&msg[e * MSG_LD + c4 * 4] = p;
            }
            const float4* er = (const float4*)(edge_attr + (size_t)rec.x * ED);
            #pragma unroll
            for (int it = 0; it < 2; ++it) {
                const int c2 = c * 2 + it;
                float4 v = er[c2];
                bf16x4_t p = {(bf16_t)v.x, (bf16_t)v.y, (bf16_t)v.z, (bf16_t)v.w};
                *(bf16x4_t*)&msg[e * MSG_LD + ND + c2 * 4] = p;
            }
        }

        // ---- GEMM1: h[0..15][0..63] = relu(msg @ W1 + b1) ----
        const int ab = col * MSG_LD + kq * 8;
        bf16x8_t af0 = *(const bf16x8_t*)&msg[ab + 0 * 32];
        bf16x8_t af1 = *(const bf16x8_t*)&msg[ab + 1 * 32];
        bf16x8_t af2 = *(const bf16x8_t*)&msg[ab + 2 * 32];
        f32x4_t acc[4];
        #pragma unroll
        for (int nt = 0; nt < 4; ++nt) {
            acc[nt] = (f32x4_t){0.0f, 0.0f, 0.0f, 0.0f};
            acc[nt] = __builtin_amdgcn_mfma_f32_16x16x32_bf16(af0, w1f[nt][0], acc[nt], 0, 0, 0);
            acc[nt] = __builtin_amdgcn_mfma_f32_16x16x32_bf16(af1, w1f[nt][1], acc[nt], 0, 0, 0);
            acc[nt] = __builtin_amdgcn_mfma_f32_16x16x32_bf16(af2, w1f[nt][2], acc[nt], 0, 0, 0);
        }
        // C/D layout: row = 4*kq + r, col = col + 16*nt
        #pragma unroll
        for (int nt = 0; nt < 4; ++nt)
            #pragma unroll
            for (int r = 0; r < 4; ++r)
                hS[(4 * kq + r) * H_LD + col + 16 * nt] =
                    (bf16_t)fmaxf(acc[nt][r] + b1r[nt], 0.0f);

        // ---- GEMM2: m = relu(h @ W2 + b2); m overwrites h in place ----
        const int hb = col * H_LD + kq * 8;
        bf16x8_t ah0 = *(const bf16x8_t*)&hS[hb + 0 * 32];
        bf16x8_t ah1 = *(const bf16x8_t*)&hS[hb + 1 * 32];
        f32x4_t acc2[4];
        #pragma unroll
        for (int nt = 0; nt < 4; ++nt) {
            acc2[nt] = (f32x4_t){0.0f, 0.0f, 0.0f, 0.0f};
            acc2[nt] = __builtin_amdgcn_mfma_f32_16x16x32_bf16(ah0, w2f[nt][0], acc2[nt], 0, 0, 0);
            acc2[nt] = __builtin_amdgcn_mfma_f32_16x16x32_bf16(ah1, w2f[nt][1], acc2[nt], 0, 0, 0);
        }
        // m stores depend on acc2 <- MFMA <- ah loads, so overlay is ordered
        #pragma unroll
        for (int nt = 0; nt < 4; ++nt)
            #pragma unroll
            for (int r = 0; r < 4; ++r)
                hS[(4 * kq + r) * H_LD + col + 16 * nt] =
                    (bf16_t)fmaxf(acc2[nt][r] + b2r[nt], 0.0f);

        // ---- segmented run-merge scatter: lane = col 0..63 over 16 sorted rows ----
        {
            int cur = dstw[0];
            float s = 0.0f;
            #pragma unroll
            for (int r = 0; r < TW; ++r) {
                const int d = dstw[r];        // wave-uniform -> uniform branch
                if (d != cur) {
                    atomicAdd(&out_sum[(size_t)cur * ND + lane], s);
                    s = 0.0f; cur = d;
                }
                s += (float)hS[r * H_LD + lane];
            }
            atomicAdd(&out_sum[(size_t)cur * ND + lane], s);
        }
    }
}

// ---------------- K5: finalize out = sum/max(cnt,1) + x ----------------
__global__ void finalize_kernel(const float* __restrict__ x,
                                const int* __restrict__ cnt,
                                float* __restrict__ out)
{
    int i = blockIdx.x * blockDim.x + threadIdx.x;
    int stride = gridDim.x * blockDim.x;
    const int total4 = NODES * ND / 4;
    for (int idx = i; idx < total4; idx += stride) {
        const int n = idx / (ND / 4);
        const float inv = 1.0f / fmaxf((float)cnt[n], 1.0f);
        float4 s = ((const float4*)out)[idx];
        float4 xv = ((const float4*)x)[idx];
        float4 r;
        r.x = s.x * inv + xv.x;
        r.y = s.y * inv + xv.y;
        r.z = s.z * inv + xv.z;
        r.w = s.w * inv + xv.w;
        ((float4*)out)[idx] = r;
    }
}

extern "C" void kernel_launch(void* const* d_in, const int* in_sizes, int n_in,
                              void* d_out, int out_size, void* d_ws, size_t ws_size,
                              hipStream_t stream) {
    const float* x  = (const float*)d_in[0];
    const int*   ei = (const int*)d_in[1];     // int64 in reference -> int32 on device
    const float* ea = (const float*)d_in[2];
    const float* W1 = (const float*)d_in[3];
    const float* b1 = (const float*)d_in[4];
    const float* W2 = (const float*)d_in[5];
    const float* b2 = (const float*)d_in[6];
    float* out = (float*)d_out;

    // d_ws layout (ints): cnt[N] | cursor[N] | pd[2E] | bsum[256]
    int*  cnt    = (int*)d_ws;
    int*  cursor = cnt + NODES;
    int2* pd     = (int2*)(cursor + NODES);
    int*  bsum   = (int*)(pd + NEDGE);

    hipLaunchKernelGGL(zero_kernel, dim3(2048), dim3(256), 0, stream, out, cnt);
    hipLaunchKernelGGL(hist_kernel, dim3(2048), dim3(256), 0, stream, ei, cnt);
    hipLaunchKernelGGL(scan_sum_kernel, dim3(SCAN_NBLK), dim3(SCAN_B), 0, stream, cnt, bsum);
    hipLaunchKernelGGL(scan_top_kernel, dim3(1), dim3(SCAN_B), 0, stream, bsum);
    hipLaunchKernelGGL(scan_fill_kernel, dim3(SCAN_NBLK), dim3(SCAN_B), 0, stream, cnt, bsum, cursor);
    hipLaunchKernelGGL(bucket_kernel, dim3(2048), dim3(256), 0, stream, ei, cursor, pd);
    hipLaunchKernelGGL(edge_mlp_mfma, dim3(1536), dim3(256), 0, stream,
                       x, ea, W1, b1, W2, b2, pd, out);
    hipLaunchKernelGGL(finalize_kernel, dim3(1600), dim3(256), 0, stream, x, cnt, out);
}

// Round 9
// 333.179 us; speedup vs baseline: 1.1290x; 1.1290x over previous
//
#include <hip/hip_runtime.h>

// Problem constants (match reference setup_inputs)
#define NODES 50000
#define NEDGE 1600000
#define ND 64      // NODE_DIM
#define ED 32      // EDGE_DIM
#define HID 64     // HIDDEN
#define IN_DIM 96  // ND + ED

#define TW 16        // edges per wave-private micro-tile
#define MSG_LD 104   // bf16/row: 96+8 pad -> 208 B rows
#define H_LD   72    // bf16/row: 64+8 pad -> 144 B rows (h and m overlay)
#define W1_LD  104   // w1T row stride (bf16): [cn][k] rows 208 B
#define W2_LD  72    // w2T row stride (bf16): 144 B

typedef __bf16 bf16_t;
typedef __bf16 bf16x4_t __attribute__((ext_vector_type(4)));
typedef __bf16 bf16x8_t __attribute__((ext_vector_type(8)));
typedef float  f32x4_t  __attribute__((ext_vector_type(4)));

#define SCAN_B 256
#define SCAN_NBLK ((NODES + SCAN_B - 1) / SCAN_B)   // 196

// ---------------- K0: zero out accumulator + counts ----------------
__global__ void zero_kernel(float* __restrict__ out, int* __restrict__ cnt) {
    int i = blockIdx.x * blockDim.x + threadIdx.x;
    int stride = gridDim.x * blockDim.x;
    const int total = NODES * ND;
    for (int idx = i; idx < total; idx += stride) out[idx] = 0.0f;
    for (int idx = i; idx < NODES; idx += stride) cnt[idx] = 0;
}

// ---------------- K1: histogram of dst ----------------
__global__ void hist_kernel(const int* __restrict__ ei, int* __restrict__ cnt) {
    int i = blockIdx.x * blockDim.x + threadIdx.x;
    int stride = gridDim.x * blockDim.x;
    for (int e = i; e < NEDGE; e += stride)
        atomicAdd(&cnt[ei[NEDGE + e]], 1);
}

// ---------------- K2a: per-block partial sums of cnt ----------------
__global__ void scan_sum_kernel(const int* __restrict__ cnt, int* __restrict__ bsum) {
    __shared__ int sh[SCAN_B];
    const int t = threadIdx.x, b = blockIdx.x;
    const int i = b * SCAN_B + t;
    sh[t] = (i < NODES) ? cnt[i] : 0;
    __syncthreads();
    for (int d = SCAN_B / 2; d > 0; d >>= 1) {
        if (t < d) sh[t] += sh[t + d];
        __syncthreads();
    }
    if (t == 0) bsum[b] = sh[0];
}

// ---------------- K2b: exclusive scan of 196 block sums (1 tiny block) ----------------
__global__ void scan_top_kernel(int* __restrict__ bsum) {
    __shared__ int sh[SCAN_B];
    const int t = threadIdx.x;
    sh[t] = (t < SCAN_NBLK) ? bsum[t] : 0;
    __syncthreads();
    for (int d = 1; d < SCAN_B; d <<= 1) {
        int v = (t >= d) ? sh[t - d] : 0;
        __syncthreads();
        sh[t] += v;
        __syncthreads();
    }
    if (t < SCAN_NBLK) bsum[t] = (t == 0) ? 0 : sh[t - 1];   // exclusive
}

// ---------------- K2c: fill cursor = global exclusive prefix of cnt ----------------
__global__ void scan_fill_kernel(const int* __restrict__ cnt, const int* __restrict__ bsum,
                                 int* __restrict__ cursor) {
    __shared__ int sh[SCAN_B];
    const int t = threadIdx.x, b = blockIdx.x;
    const int i = b * SCAN_B + t;
    int v = (i < NODES) ? cnt[i] : 0;
    sh[t] = v;
    __syncthreads();
    for (int d = 1; d < SCAN_B; d <<= 1) {
        int u = (t >= d) ? sh[t - d] : 0;
        __syncthreads();
        sh[t] += u;
        __syncthreads();
    }
    if (i < NODES) cursor[i] = bsum[b] + sh[t] - v;   // exclusive
}

// ---------------- K3: bucket-scatter edge ids (CSR perm, packed int2) ----------------
__global__ void bucket_kernel(const int* __restrict__ ei, int* __restrict__ cursor,
                              int2* __restrict__ pd) {
    int i = blockIdx.x * blockDim.x + threadIdx.x;
    int stride = gridDim.x * blockDim.x;
    for (int e = i; e < NEDGE; e += stride) {
        int d = ei[NEDGE + e];
        int pos = atomicAdd(&cursor[d], 1);
        pd[pos] = make_int2(e, d);
    }
}

// ---------------- K4: per-edge MLP via bf16 MFMA — wave-private tiles, LDS weights ----------------
// One barrier total (after weight staging). Weights live in LDS (shared per block)
// to keep VGPRs <=128 -> 4 waves/SIMD. Each wave owns a 16-edge micro-tile.
__global__ __launch_bounds__(256, 4)
void edge_mlp_mfma(const float* __restrict__ x,
                   const float* __restrict__ edge_attr,
                   const float* __restrict__ W1, const float* __restrict__ b1,
                   const float* __restrict__ W2, const float* __restrict__ b2,
                   const int2* __restrict__ pd,
                   float* __restrict__ out_sum)
{
    __shared__ __align__(16) bf16_t w1T[HID * W1_LD];       // [cn][k] 13312 B
    __shared__ __align__(16) bf16_t w2T[ND * W2_LD];        // [cn][k]  9216 B
    __shared__ __align__(16) bf16_t msg_all[4 * TW * MSG_LD]; // per-wave [16][104] 13312 B
    __shared__ int dstw_all[4 * TW];

    const int t    = threadIdx.x;
    const int lane = t & 63;
    const int w    = t >> 6;         // wave id 0..3
    const int col  = lane & 15;      // MFMA col / A-row selector
    const int kq   = lane >> 4;      // 0..3: k-quarter

    bf16_t* msg  = msg_all + w * TW * MSG_LD;   // [16][MSG_LD]
    bf16_t* hS   = msg;                          // [16][H_LD] overlay (h, then m)
    int*    dstw = dstw_all + w * TW;

    // ---- one-time: transpose W1,W2 into LDS (bf16) ----
    for (int i = t; i < IN_DIM * HID / 4; i += 256) {
        float4 v = ((const float4*)W1)[i];
        int k = i >> 4, j4 = (i & 15) * 4;      // W1[k][j4..j4+3]
        w1T[(j4 + 0) * W1_LD + k] = (bf16_t)v.x;
        w1T[(j4 + 1) * W1_LD + k] = (bf16_t)v.y;
        w1T[(j4 + 2) * W1_LD + k] = (bf16_t)v.z;
        w1T[(j4 + 3) * W1_LD + k] = (bf16_t)v.w;
    }
    for (int i = t; i < HID * ND / 4; i += 256) {
        float4 v = ((const float4*)W2)[i];
        int k = i >> 4, j4 = (i & 15) * 4;
        w2T[(j4 + 0) * W2_LD + k] = (bf16_t)v.x;
        w2T[(j4 + 1) * W2_LD + k] = (bf16_t)v.y;
        w2T[(j4 + 2) * W2_LD + k] = (bf16_t)v.z;
        w2T[(j4 + 3) * W2_LD + k] = (bf16_t)v.w;
    }
    float b1r[4], b2r[4];
    #pragma unroll
    for (int nt = 0; nt < 4; ++nt) {
        b1r[nt] = b1[col + 16 * nt];
        b2r[nt] = b2[col + 16 * nt];
    }
    __syncthreads();   // the only block barrier

    const int ntiles = NEDGE / TW;               // 100000
    const int wid = blockIdx.x * 4 + w;
    const int nw  = gridDim.x * 4;

    for (int tile = wid; tile < ntiles; tile += nw) {
        const int eb = tile * TW;

        if (lane < TW) dstw[lane] = pd[eb + lane].y;

        // ---- stage msg micro-tile (bf16): 4 lanes per edge row ----
        {
            const int e = lane >> 2, c = lane & 3;
            const int2 rec = pd[eb + e];
            const float4* xr = (const float4*)(x + (size_t)rec.y * ND);
            #pragma unroll
            for (int it = 0; it < 4; ++it) {
                const int c4 = c + it * 4;
                float4 v = xr[c4];
                bf16x4_t p = {(bf16_t)v.x, (bf16_t)v.y, (bf16_t)v.z, (bf16_t)v.w};
                *(bf16x4_t*)&msg[e * MSG_LD + c4 * 4] = p;
            }
            const float4* er = (const float4*)(edge_attr + (size_t)rec.x * ED);
            #pragma unroll
            for (int it = 0; it < 2; ++it) {
                const int c2 = c * 2 + it;
                float4 v = er[c2];
                bf16x4_t p = {(bf16_t)v.x, (bf16_t)v.y, (bf16_t)v.z, (bf16_t)v.w};
                *(bf16x4_t*)&msg[e * MSG_LD + ND + c2 * 4] = p;
            }
        }

        // ---- GEMM1: h[0..15][0..63] = relu(msg @ W1 + b1) ----
        const int ab = col * MSG_LD + kq * 8;
        bf16x8_t af0 = *(const bf16x8_t*)&msg[ab + 0 * 32];
        bf16x8_t af1 = *(const bf16x8_t*)&msg[ab + 1 * 32];
        bf16x8_t af2 = *(const bf16x8_t*)&msg[ab + 2 * 32];
        f32x4_t acc[4];
        #pragma unroll
        for (int nt = 0; nt < 4; ++nt) {
            const bf16_t* wrow = &w1T[(col + 16 * nt) * W1_LD + kq * 8];
            bf16x8_t f0 = *(const bf16x8_t*)(wrow + 0 * 32);
            bf16x8_t f1 = *(const bf16x8_t*)(wrow + 1 * 32);
            bf16x8_t f2 = *(const bf16x8_t*)(wrow + 2 * 32);
            acc[nt] = (f32x4_t){0.0f, 0.0f, 0.0f, 0.0f};
            acc[nt] = __builtin_amdgcn_mfma_f32_16x16x32_bf16(af0, f0, acc[nt], 0, 0, 0);
            acc[nt] = __builtin_amdgcn_mfma_f32_16x16x32_bf16(af1, f1, acc[nt], 0, 0, 0);
            acc[nt] = __builtin_amdgcn_mfma_f32_16x16x32_bf16(af2, f2, acc[nt], 0, 0, 0);
        }
        // C/D layout: row = 4*kq + r, col = col + 16*nt
        #pragma unroll
        for (int nt = 0; nt < 4; ++nt)
            #pragma unroll
            for (int r = 0; r < 4; ++r)
                hS[(4 * kq + r) * H_LD + col + 16 * nt] =
                    (bf16_t)fmaxf(acc[nt][r] + b1r[nt], 0.0f);

        // ---- GEMM2: m = relu(h @ W2 + b2); m overwrites h in place ----
        const int hb = col * H_LD + kq * 8;
        bf16x8_t ah0 = *(const bf16x8_t*)&hS[hb + 0 * 32];
        bf16x8_t ah1 = *(const bf16x8_t*)&hS[hb + 1 * 32];
        f32x4_t acc2[4];
        #pragma unroll
        for (int nt = 0; nt < 4; ++nt) {
            const bf16_t* wrow = &w2T[(col + 16 * nt) * W2_LD + kq * 8];
            bf16x8_t f0 = *(const bf16x8_t*)(wrow + 0 * 32);
            bf16x8_t f1 = *(const bf16x8_t*)(wrow + 1 * 32);
            acc2[nt] = (f32x4_t){0.0f, 0.0f, 0.0f, 0.0f};
            acc2[nt] = __builtin_amdgcn_mfma_f32_16x16x32_bf16(ah0, f0, acc2[nt], 0, 0, 0);
            acc2[nt] = __builtin_amdgcn_mfma_f32_16x16x32_bf16(ah1, f1, acc2[nt], 0, 0, 0);
        }
        // LDS ops are in-order per wave -> overlay m-over-h is safe
        #pragma unroll
        for (int nt = 0; nt < 4; ++nt)
            #pragma unroll
            for (int r = 0; r < 4; ++r)
                hS[(4 * kq + r) * H_LD + col + 16 * nt] =
                    (bf16_t)fmaxf(acc2[nt][r] + b2r[nt], 0.0f);

        // ---- segmented run-merge scatter: lane = col 0..63 over 16 sorted rows ----
        {
            int cur = __builtin_amdgcn_readfirstlane(dstw[0]);
            float s = 0.0f;
            #pragma unroll
            for (int r = 0; r < TW; ++r) {
                const int d = __builtin_amdgcn_readfirstlane(dstw[r]);  // uniform -> scalar branch
                if (d != cur) {
                    atomicAdd(&out_sum[(size_t)cur * ND + lane], s);
                    s = 0.0f; cur = d;
                }
                s += (float)hS[r * H_LD + lane];
            }
            atomicAdd(&out_sum[(size_t)cur * ND + lane], s);
        }
    }
}

// ---------------- K5: finalize out = sum/max(cnt,1) + x ----------------
__global__ void finalize_kernel(const float* __restrict__ x,
                                const int* __restrict__ cnt,
                                float* __restrict__ out)
{
    int i = blockIdx.x * blockDim.x + threadIdx.x;
    int stride = gridDim.x * blockDim.x;
    const int total4 = NODES * ND / 4;
    for (int idx = i; idx < total4; idx += stride) {
        const int n = idx / (ND / 4);
        const float inv = 1.0f / fmaxf((float)cnt[n], 1.0f);
        float4 s = ((const float4*)out)[idx];
        float4 xv = ((const float4*)x)[idx];
        float4 r;
        r.x = s.x * inv + xv.x;
        r.y = s.y * inv + xv.y;
        r.z = s.z * inv + xv.z;
        r.w = s.w * inv + xv.w;
        ((float4*)out)[idx] = r;
    }
}

extern "C" void kernel_launch(void* const* d_in, const int* in_sizes, int n_in,
                              void* d_out, int out_size, void* d_ws, size_t ws_size,
                              hipStream_t stream) {
    const float* x  = (const float*)d_in[0];
    const int*   ei = (const int*)d_in[1];     // int64 in reference -> int32 on device
    const float* ea = (const float*)d_in[2];
    const float* W1 = (const float*)d_in[3];
    const float* b1 = (const float*)d_in[4];
    const float* W2 = (const float*)d_in[5];
    const float* b2 = (const float*)d_in[6];
    float* out = (float*)d_out;

    // d_ws layout (ints): cnt[N] | cursor[N] | pd[2E] | bsum[256]
    int*  cnt    = (int*)d_ws;
    int*  cursor = cnt + NODES;
    int2* pd     = (int2*)(cursor + NODES);
    int*  bsum   = (int*)(pd + NEDGE);

    hipLaunchKernelGGL(zero_kernel, dim3(2048), dim3(256), 0, stream, out, cnt);
    hipLaunchKernelGGL(hist_kernel, dim3(2048), dim3(256), 0, stream, ei, cnt);
    hipLaunchKernelGGL(scan_sum_kernel, dim3(SCAN_NBLK), dim3(SCAN_B), 0, stream, cnt, bsum);
    hipLaunchKernelGGL(scan_top_kernel, dim3(1), dim3(SCAN_B), 0, stream, bsum);
    hipLaunchKernelGGL(scan_fill_kernel, dim3(SCAN_NBLK), dim3(SCAN_B), 0, stream, cnt, bsum, cursor);
    hipLaunchKernelGGL(bucket_kernel, dim3(2048), dim3(256), 0, stream, ei, cursor, pd);
    hipLaunchKernelGGL(edge_mlp_mfma, dim3(1024), dim3(256), 0, stream,
                       x, ea, W1, b1, W2, b2, pd, out);
    hipLaunchKernelGGL(finalize_kernel, dim3(1600), dim3(256), 0, stream, x, cnt, out);
}

// Round 10
// 271.452 us; speedup vs baseline: 1.3858x; 1.2274x over previous
//
#include <hip/hip_runtime.h>

// Problem constants (match reference setup_inputs)
#define NODES 50000
#define NEDGE 1600000
#define ND 64      // NODE_DIM
#define ED 32      // EDGE_DIM
#define HID 64     // HIDDEN
#define IN_DIM 96  // ND + ED

#define TW 16        // edges per wave-private micro-tile
#define MSG_LD 104   // bf16/row: 96+8 pad -> 208 B rows
#define H_LD   72    // bf16/row: 64+8 pad -> 144 B rows (h and m overlay)
#define W1_LD  104   // w1T row stride (bf16): [cn][k] rows 208 B
#define W2_LD  72    // w2T row stride (bf16): 144 B

typedef __bf16 bf16_t;
typedef __bf16 bf16x4_t __attribute__((ext_vector_type(4)));
typedef __bf16 bf16x8_t __attribute__((ext_vector_type(8)));
typedef float  f32x4_t  __attribute__((ext_vector_type(4)));

#define SCAN_B 256
#define SCAN_NBLK ((NODES + SCAN_B - 1) / SCAN_B)   // 196

#define NXCD 8
#define NODES_PER_G ((NODES + NXCD - 1) / NXCD)   // 6250

// ---------------- K0: zero out accumulator + counts ----------------
__global__ void zero_kernel(float* __restrict__ out, int* __restrict__ cnt) {
    int i = blockIdx.x * blockDim.x + threadIdx.x;
    int stride = gridDim.x * blockDim.x;
    const int total = NODES * ND;
    for (int idx = i; idx < total; idx += stride) out[idx] = 0.0f;
    for (int idx = i; idx < NODES; idx += stride) cnt[idx] = 0;
}

// ---------------- K1: histogram of dst ----------------
__global__ void hist_kernel(const int* __restrict__ ei, int* __restrict__ cnt) {
    int i = blockIdx.x * blockDim.x + threadIdx.x;
    int stride = gridDim.x * blockDim.x;
    for (int e = i; e < NEDGE; e += stride)
        atomicAdd(&cnt[ei[NEDGE + e]], 1);
}

// ---------------- K2a: per-block partial sums of cnt ----------------
__global__ void scan_sum_kernel(const int* __restrict__ cnt, int* __restrict__ bsum) {
    __shared__ int sh[SCAN_B];
    const int t = threadIdx.x, b = blockIdx.x;
    const int i = b * SCAN_B + t;
    sh[t] = (i < NODES) ? cnt[i] : 0;
    __syncthreads();
    for (int d = SCAN_B / 2; d > 0; d >>= 1) {
        if (t < d) sh[t] += sh[t + d];
        __syncthreads();
    }
    if (t == 0) bsum[b] = sh[0];
}

// ---------------- K2b: exclusive scan of 196 block sums (1 tiny block) ----------------
__global__ void scan_top_kernel(int* __restrict__ bsum) {
    __shared__ int sh[SCAN_B];
    const int t = threadIdx.x;
    sh[t] = (t < SCAN_NBLK) ? bsum[t] : 0;
    __syncthreads();
    for (int d = 1; d < SCAN_B; d <<= 1) {
        int v = (t >= d) ? sh[t - d] : 0;
        __syncthreads();
        sh[t] += v;
        __syncthreads();
    }
    if (t < SCAN_NBLK) bsum[t] = (t == 0) ? 0 : sh[t - 1];   // exclusive
}

// ---------------- K2c: fill cursor = global exclusive prefix of cnt ----------------
__global__ void scan_fill_kernel(const int* __restrict__ cnt, const int* __restrict__ bsum,
                                 int* __restrict__ cursor) {
    __shared__ int sh[SCAN_B];
    const int t = threadIdx.x, b = blockIdx.x;
    const int i = b * SCAN_B + t;
    int v = (i < NODES) ? cnt[i] : 0;
    sh[t] = v;
    __syncthreads();
    for (int d = 1; d < SCAN_B; d <<= 1) {
        int u = (t >= d) ? sh[t - d] : 0;
        __syncthreads();
        sh[t] += u;
        __syncthreads();
    }
    if (i < NODES) cursor[i] = bsum[b] + sh[t] - v;   // exclusive
}

// ---------------- K3: bucket-scatter, XCD-partitioned by dst range ----------------
// Group g = blockIdx&7 (presumed XCD round-robin) handles dst in its 1/8 node
// range only -> each XCD's pd writes confined to ~1.6 MB (L2-resident, kills
// the 8x per-XCD write amplification). Each group re-reads the dst row (8x6.4MB).
__global__ void bucket_kernel(const int* __restrict__ ei, int* __restrict__ cursor,
                              int2* __restrict__ pd) {
    const int g   = blockIdx.x & (NXCD - 1);
    const int bg  = blockIdx.x >> 3;            // block index within group
    const int bpg = gridDim.x >> 3;             // blocks per group
    const int lo  = g * NODES_PER_G;
    const int hi  = min(lo + NODES_PER_G, NODES);
    int i = bg * blockDim.x + threadIdx.x;
    int stride = bpg * blockDim.x;
    for (int e = i; e < NEDGE; e += stride) {
        int d = ei[NEDGE + e];
        if (d >= lo && d < hi) {
            int pos = atomicAdd(&cursor[d], 1);
            pd[pos] = make_int2(e, d);
        }
    }
}

// ---------------- K4: per-edge MLP via bf16 MFMA — wave-private tiles, LDS weights ----------------
// One barrier total (after weight staging). Weights live in LDS (shared per block)
// to keep VGPRs <=128 -> 4 waves/SIMD. Each wave owns a 16-edge micro-tile.
__global__ __launch_bounds__(256, 4)
void edge_mlp_mfma(const float* __restrict__ x,
                   const float* __restrict__ edge_attr,
                   const float* __restrict__ W1, const float* __restrict__ b1,
                   const float* __restrict__ W2, const float* __restrict__ b2,
                   const int2* __restrict__ pd,
                   float* __restrict__ out_sum)
{
    __shared__ __align__(16) bf16_t w1T[HID * W1_LD];       // [cn][k] 13312 B
    __shared__ __align__(16) bf16_t w2T[ND * W2_LD];        // [cn][k]  9216 B
    __shared__ __align__(16) bf16_t msg_all[4 * TW * MSG_LD]; // per-wave [16][104] 13312 B
    __shared__ int dstw_all[4 * TW];

    const int t    = threadIdx.x;
    const int lane = t & 63;
    const int w    = t >> 6;         // wave id 0..3
    const int col  = lane & 15;      // MFMA col / A-row selector
    const int kq   = lane >> 4;      // 0..3: k-quarter

    bf16_t* msg  = msg_all + w * TW * MSG_LD;   // [16][MSG_LD]
    bf16_t* hS   = msg;                          // [16][H_LD] overlay (h, then m)
    int*    dstw = dstw_all + w * TW;

    // ---- one-time: transpose W1,W2 into LDS (bf16) ----
    for (int i = t; i < IN_DIM * HID / 4; i += 256) {
        float4 v = ((const float4*)W1)[i];
        int k = i >> 4, j4 = (i & 15) * 4;      // W1[k][j4..j4+3]
        w1T[(j4 + 0) * W1_LD + k] = (bf16_t)v.x;
        w1T[(j4 + 1) * W1_LD + k] = (bf16_t)v.y;
        w1T[(j4 + 2) * W1_LD + k] = (bf16_t)v.z;
        w1T[(j4 + 3) * W1_LD + k] = (bf16_t)v.w;
    }
    for (int i = t; i < HID * ND / 4; i += 256) {
        float4 v = ((const float4*)W2)[i];
        int k = i >> 4, j4 = (i & 15) * 4;
        w2T[(j4 + 0) * W2_LD + k] = (bf16_t)v.x;
        w2T[(j4 + 1) * W2_LD + k] = (bf16_t)v.y;
        w2T[(j4 + 2) * W2_LD + k] = (bf16_t)v.z;
        w2T[(j4 + 3) * W2_LD + k] = (bf16_t)v.w;
    }
    float b1r[4], b2r[4];
    #pragma unroll
    for (int nt = 0; nt < 4; ++nt) {
        b1r[nt] = b1[col + 16 * nt];
        b2r[nt] = b2[col + 16 * nt];
    }
    __syncthreads();   // the only block barrier

    const int ntiles = NEDGE / TW;               // 100000
    const int wid = blockIdx.x * 4 + w;
    const int nw  = gridDim.x * 4;

    for (int tile = wid; tile < ntiles; tile += nw) {
        const int eb = tile * TW;

        if (lane < TW) dstw[lane] = pd[eb + lane].y;

        // ---- stage msg micro-tile (bf16): 4 lanes per edge row ----
        {
            const int e = lane >> 2, c = lane & 3;
            const int2 rec = pd[eb + e];
            const float4* xr = (const float4*)(x + (size_t)rec.y * ND);
            #pragma unroll
            for (int it = 0; it < 4; ++it) {
                const int c4 = c + it * 4;
                float4 v = xr[c4];
                bf16x4_t p = {(bf16_t)v.x, (bf16_t)v.y, (bf16_t)v.z, (bf16_t)v.w};
                *(bf16x4_t*)&msg[e * MSG_LD + c4 * 4] = p;
            }
            const float4* er = (const float4*)(edge_attr + (size_t)rec.x * ED);
            #pragma unroll
            for (int it = 0; it < 2; ++it) {
                const int c2 = c * 2 + it;
                float4 v = er[c2];
                bf16x4_t p = {(bf16_t)v.x, (bf16_t)v.y, (bf16_t)v.z, (bf16_t)v.w};
                *(bf16x4_t*)&msg[e * MSG_LD + ND + c2 * 4] = p;
            }
        }

        // ---- GEMM1: h[0..15][0..63] = relu(msg @ W1 + b1) ----
        const int ab = col * MSG_LD + kq * 8;
        bf16x8_t af0 = *(const bf16x8_t*)&msg[ab + 0 * 32];
        bf16x8_t af1 = *(const bf16x8_t*)&msg[ab + 1 * 32];
        bf16x8_t af2 = *(const bf16x8_t*)&msg[ab + 2 * 32];
        f32x4_t acc[4];
        #pragma unroll
        for (int nt = 0; nt < 4; ++nt) {
            const bf16_t* wrow = &w1T[(col + 16 * nt) * W1_LD + kq * 8];
            bf16x8_t f0 = *(const bf16x8_t*)(wrow + 0 * 32);
            bf16x8_t f1 = *(const bf16x8_t*)(wrow + 1 * 32);
            bf16x8_t f2 = *(const bf16x8_t*)(wrow + 2 * 32);
            acc[nt] = (f32x4_t){0.0f, 0.0f, 0.0f, 0.0f};
            acc[nt] = __builtin_amdgcn_mfma_f32_16x16x32_bf16(af0, f0, acc[nt], 0, 0, 0);
            acc[nt] = __builtin_amdgcn_mfma_f32_16x16x32_bf16(af1, f1, acc[nt], 0, 0, 0);
            acc[nt] = __builtin_amdgcn_mfma_f32_16x16x32_bf16(af2, f2, acc[nt], 0, 0, 0);
        }
        // C/D layout: row = 4*kq + r, col = col + 16*nt
        #pragma unroll
        for (int nt = 0; nt < 4; ++nt)
            #pragma unroll
            for (int r = 0; r < 4; ++r)
                hS[(4 * kq + r) * H_LD + col + 16 * nt] =
                    (bf16_t)fmaxf(acc[nt][r] + b1r[nt], 0.0f);

        // ---- GEMM2: m = relu(h @ W2 + b2); m overwrites h in place ----
        const int hb = col * H_LD + kq * 8;
        bf16x8_t ah0 = *(const bf16x8_t*)&hS[hb + 0 * 32];
        bf16x8_t ah1 = *(const bf16x8_t*)&hS[hb + 1 * 32];
        f32x4_t acc2[4];
        #pragma unroll
        for (int nt = 0; nt < 4; ++nt) {
            const bf16_t* wrow = &w2T[(col + 16 * nt) * W2_LD + kq * 8];
            bf16x8_t f0 = *(const bf16x8_t*)(wrow + 0 * 32);
            bf16x8_t f1 = *(const bf16x8_t*)(wrow + 1 * 32);
            acc2[nt] = (f32x4_t){0.0f, 0.0f, 0.0f, 0.0f};
            acc2[nt] = __builtin_amdgcn_mfma_f32_16x16x32_bf16(ah0, f0, acc2[nt], 0, 0, 0);
            acc2[nt] = __builtin_amdgcn_mfma_f32_16x16x32_bf16(ah1, f1, acc2[nt], 0, 0, 0);
        }
        // LDS ops are in-order per wave -> overlay m-over-h is safe
        #pragma unroll
        for (int nt = 0; nt < 4; ++nt)
            #pragma unroll
            for (int r = 0; r < 4; ++r)
                hS[(4 * kq + r) * H_LD + col + 16 * nt] =
                    (bf16_t)fmaxf(acc2[nt][r] + b2r[nt], 0.0f);

        // ---- segmented run-merge scatter: lane = col 0..63 over 16 sorted rows ----
        {
            int cur = __builtin_amdgcn_readfirstlane(dstw[0]);
            float s = 0.0f;
            #pragma unroll
            for (int r = 0; r < TW; ++r) {
                const int d = __builtin_amdgcn_readfirstlane(dstw[r]);  // uniform -> scalar branch
                if (d != cur) {
                    atomicAdd(&out_sum[(size_t)cur * ND + lane], s);
                    s = 0.0f; cur = d;
                }
                s += (float)hS[r * H_LD + lane];
            }
            atomicAdd(&out_sum[(size_t)cur * ND + lane], s);
        }
    }
}

// ---------------- K5: finalize out = sum/max(cnt,1) + x ----------------
__global__ void finalize_kernel(const float* __restrict__ x,
                                const int* __restrict__ cnt,
                                float* __restrict__ out)
{
    int i = blockIdx.x * blockDim.x + threadIdx.x;
    int stride = gridDim.x * blockDim.x;
    const int total4 = NODES * ND / 4;
    for (int idx = i; idx < total4; idx += stride) {
        const int n = idx / (ND / 4);
        const float inv = 1.0f / fmaxf((float)cnt[n], 1.0f);
        float4 s = ((const float4*)out)[idx];
        float4 xv = ((const float4*)x)[idx];
        float4 r;
        r.x = s.x * inv + xv.x;
        r.y = s.y * inv + xv.y;
        r.z = s.z * inv + xv.z;
        r.w = s.w * inv + xv.w;
        ((float4*)out)[idx] = r;
    }
}

extern "C" void kernel_launch(void* const* d_in, const int* in_sizes, int n_in,
                              void* d_out, int out_size, void* d_ws, size_t ws_size,
                              hipStream_t stream) {
    const float* x  = (const float*)d_in[0];
    const int*   ei = (const int*)d_in[1];     // int64 in reference -> int32 on device
    const float* ea = (const float*)d_in[2];
    const float* W1 = (const float*)d_in[3];
    const float* b1 = (const float*)d_in[4];
    const float* W2 = (const float*)d_in[5];
    const float* b2 = (const float*)d_in[6];
    float* out = (float*)d_out;

    // d_ws layout (ints): cnt[N] | cursor[N] | pd[2E] | bsum[256]
    int*  cnt    = (int*)d_ws;
    int*  cursor = cnt + NODES;
    int2* pd     = (int2*)(cursor + NODES);
    int*  bsum   = (int*)(pd + NEDGE);

    hipLaunchKernelGGL(zero_kernel, dim3(2048), dim3(256), 0, stream, out, cnt);
    hipLaunchKernelGGL(hist_kernel, dim3(2048), dim3(256), 0, stream, ei, cnt);
    hipLaunchKernelGGL(scan_sum_kernel, dim3(SCAN_NBLK), dim3(SCAN_B), 0, stream, cnt, bsum);
    hipLaunchKernelGGL(scan_top_kernel, dim3(1), dim3(SCAN_B), 0, stream, bsum);
    hipLaunchKernelGGL(scan_fill_kernel, dim3(SCAN_NBLK), dim3(SCAN_B), 0, stream, cnt, bsum, cursor);
    hipLaunchKernelGGL(bucket_kernel, dim3(2048), dim3(256), 0, stream, ei, cursor, pd);
    hipLaunchKernelGGL(edge_mlp_mfma, dim3(1024), dim3(256), 0, stream,
                       x, ea, W1, b1, W2, b2, pd, out);
    hipLaunchKernelGGL(finalize_kernel, dim3(1600), dim3(256), 0, stream, x, cnt, out);
}